// Round 8
// baseline (2525.871 us; speedup 1.0000x reference)
//
#include <hip/hip_runtime.h>

// BertEmbedding + 5-layer GAT on MI355X (gfx950). Round 8: FULL FUSION.
// One persistent kernel (512 blocks x 256 thr, guaranteed 2 blocks/CU via
// __launch_bounds__(256,2): LDS 24.6KB<=80KB, VGPR<=256) runs all phases --
// setup (fold/nodes/csr), prep (5 layers' split-bf16 B), 5x(MFMA gemm + gat),
// final layernorm -- separated by a manual device-scope grid barrier
// (sense-reversing, agent-scope atomics + __threadfence on each block
// leader's CU). Math bit-identical to round-7 (absmax must stay 0.015625).
// Purpose: removes 11 dispatch boundaries AND makes the pipeline's true cost
// visible as a single dispatch in the profile (decides kernel-time vs
// harness-fixed-overhead split of the ~330us residual).

#define DEV __device__ __forceinline__
#define NB 512

typedef short s16x8 __attribute__((ext_vector_type(8)));
typedef float f32x4 __attribute__((ext_vector_type(4)));

DEV float b2f(unsigned int u) { union { unsigned int i; float f; } v; v.i = u << 16; return v.f; }
DEV unsigned short f2b(float f) {
  union { float f; unsigned int i; } v; v.f = f;
  return (unsigned short)((v.i + 0x7fffu + ((v.i >> 16) & 1u)) >> 16);
}
DEV float gelu_exact(float x) { return 0.5f * x * (1.f + erff(x * 0.70710678118654752f)); }

DEV float ldf(const void* p, size_t i, int fF) {
  return fF ? ((const float*)p)[i] : b2f(((const unsigned short*)p)[i]);
}
DEV int ldi(const void* p, size_t i, int fI) {
  return fI ? ((const int*)p)[2 * i] : ((const int*)p)[i];
}

// Device-scope grid barrier. All NB blocks are co-resident by construction.
// Leader thread: release-fence own CU/L2, arrive; last resets count and bumps
// generation; others spin (s_sleep) on generation with acquire; acquire-fence
// before any thread reads cross-block data.
DEV void gbar(int* bar) {
  __syncthreads();
  if (threadIdx.x == 0) {
    __threadfence();
    int g = __hip_atomic_load(&bar[1], __ATOMIC_RELAXED, __HIP_MEMORY_SCOPE_AGENT);
    int a = __hip_atomic_fetch_add(&bar[0], 1, __ATOMIC_ACQ_REL, __HIP_MEMORY_SCOPE_AGENT);
    if (a == NB - 1) {
      __hip_atomic_store(&bar[0], 0, __ATOMIC_RELAXED, __HIP_MEMORY_SCOPE_AGENT);
      __hip_atomic_fetch_add(&bar[1], 1, __ATOMIC_RELEASE, __HIP_MEMORY_SCOPE_AGENT);
    } else {
      while (__hip_atomic_load(&bar[1], __ATOMIC_ACQUIRE, __HIP_MEMORY_SCOPE_AGENT) == g)
        __builtin_amdgcn_s_sleep(16);
    }
    __threadfence();
  }
  __syncthreads();
}

__global__ __launch_bounds__(256, 2) void k_all(
    const void* __restrict__ src, const void* __restrict__ seg,
    const void* __restrict__ typ, const void* __restrict__ pos,
    const void* __restrict__ sst, const void* __restrict__ sen,
    const void* __restrict__ edge, const void* __restrict__ word,
    const void* __restrict__ post, const void* __restrict__ segt,
    const void* __restrict__ typt, const void* __restrict__ gamma,
    const void* __restrict__ beta, const void* __restrict__ Wg,
    const void* __restrict__ aS, const void* __restrict__ aD,
    const void* __restrict__ bG,
    float* __restrict__ F, unsigned short* __restrict__ xh,
    unsigned short* __restrict__ xl, unsigned short* __restrict__ Bh,
    unsigned short* __restrict__ Bl, float* __restrict__ C,
    float* __restrict__ xf, int* __restrict__ csr_off,
    int* __restrict__ csr_src, int* __restrict__ bar,
    void* __restrict__ out) {
  __shared__ __align__(16) char smem[24576];
  __shared__ int sflags[2];
  int t = threadIdx.x, bid = blockIdx.x;
  int wave = t >> 6, lane = t & 63;

  // ---- local dtype detection (every block; ~1KB cached reads) ----
  if (t < 64) {
    const unsigned short* w16 = (const unsigned short*)word;
    int crazy = 0;
    for (int i = t; i < 512; i += 64) {
      unsigned int e = (w16[i] >> 7) & 0xffu;
      if (e >= 135u || (e >= 1u && e <= 100u)) crazy++;
    }
#pragma unroll
    for (int o = 32; o > 0; o >>= 1) crazy += __shfl_down(crazy, o);
    if (t == 0) {
      sflags[0] = (crazy >= 8) ? 1 : 0;
      sflags[1] = (((const int*)pos)[1] == 0) ? 1 : 0;
    }
  }
  __syncthreads();
  const int fF = sflags[0], fI = sflags[1];

  // ================= P0a: fold -> F (wave-per-row, 2 passes) =============
  {
    float* sA = (float*)smem;
    float* sD = sA + 768;
    for (int pass = 0; pass < 2; ++pass) {
      int blk = bid + NB * pass;
      if (blk < 960) {
        int R0 = blk * 4, l = R0 / 768;
        __syncthreads();
        for (int i = t; i < 768; i += 256) {
          sA[i] = ldf(aS, (size_t)l * 768 + i, fF);
          sD[i] = ldf(aD, (size_t)l * 768 + i, fF);
        }
        __syncthreads();
        int k = (R0 + wave) - l * 768;
        size_t wbase = ((size_t)l * 768 + k) * 768;
        float accS[4] = {0.f, 0.f, 0.f, 0.f}, accD[4] = {0.f, 0.f, 0.f, 0.f};
#pragma unroll
        for (int i = 0; i < 12; ++i) {
          int d = lane + 64 * i;
          float w = ldf(Wg, wbase + d, fF);
          accS[i / 3] += w * sA[d];
          accD[i / 3] += w * sD[d];
        }
        float* Fl = F + (size_t)l * 8 * 768;
#pragma unroll
        for (int h = 0; h < 4; ++h) {
          float sS = accS[h], sDv = accD[h];
#pragma unroll
          for (int o = 32; o > 0; o >>= 1) {
            sS += __shfl_down(sS, o);
            sDv += __shfl_down(sDv, o);
          }
          if (lane == 0) {
            Fl[(size_t)h * 768 + k] = sS;
            Fl[(size_t)(4 + h) * 768 + k] = sDv;
          }
        }
      }
    }
  }

  // ================= P0b: nodes -> xh/xl ================================
  for (int g = bid; g < 576; g += NB) {
    int b = g / 9, j = g % 9;
    float v[3] = {0.f, 0.f, 0.f};
    if (j == 0) {
      int r = ldi(src, (size_t)b * 512, fI);
#pragma unroll
      for (int ii = 0; ii < 3; ++ii) v[ii] = ldf(word, (size_t)r * 768 + t + 256 * ii, fF);
    } else {
      int st = ldi(sst, (size_t)b * 8 + j - 1, fI);
      int en = ldi(sen, (size_t)b * 8 + j - 1, fI);
      for (int s = st; s <= en; ++s) {
        int r = ldi(src, (size_t)b * 512 + s, fI);
#pragma unroll
        for (int ii = 0; ii < 3; ++ii) v[ii] += ldf(word, (size_t)r * 768 + t + 256 * ii, fF);
      }
    }
#pragma unroll
    for (int ii = 0; ii < 3; ++ii) {
      float g0 = v[ii];
      unsigned short hi = f2b(g0);
      size_t o = (size_t)g * 768 + t + 256 * ii;
      xh[o] = hi;
      xl[o] = f2b(g0 - b2f((unsigned int)hi));
    }
  }

  // ================= P0c: CSR (last block only) ==========================
  if (bid == NB - 1) {
    __syncthreads();
    int* cnt = (int*)smem;
    int* off = cnt + 576;
    int* fill = off + 577;
    for (int i = t; i < 576; i += 256) cnt[i] = 0;
    __syncthreads();
    for (int e = t; e < 8768; e += 256) {
      int di;
      if (e < 4096) di = ldi(edge, (size_t)4096 + e, fI);
      else if (e < 8192) di = ldi(edge, (size_t)e - 4096, fI);
      else di = e - 8192;
      atomicAdd(&cnt[di], 1);
    }
    __syncthreads();
    if (t < 64) {  // wave-parallel exclusive scan of 576 = 9*64 counts
      int base = 0;
      for (int c = 0; c < 9; ++c) {
        int cv = cnt[c * 64 + t];
        int v = cv;
#pragma unroll
        for (int o = 1; o < 64; o <<= 1) {
          int u = __shfl_up(v, o);
          if (t >= (unsigned)o) v += u;
        }
        off[c * 64 + t] = base + v - cv;
        base += __shfl(v, 63);
      }
      if (t == 0) off[576] = base;
    }
    __syncthreads();
    for (int i = t; i < 577; i += 256) csr_off[i] = off[i];
    for (int i = t; i < 576; i += 256) fill[i] = off[i];
    __syncthreads();
    for (int e = t; e < 8768; e += 256) {
      int si, di;
      if (e < 4096)      { si = ldi(edge, (size_t)e, fI); di = ldi(edge, (size_t)4096 + e, fI); }
      else if (e < 8192) { si = ldi(edge, (size_t)e, fI); di = ldi(edge, (size_t)e - 4096, fI); }
      else               { si = e - 8192;                 di = si; }
      int p = atomicAdd(&fill[di], 1);
      csr_src[p] = si;
    }
  }

  gbar(bar);

  // ================= P1: prep all 5 layers' Bh/Bl ========================
  {
    float(*tile)[65] = (float(*)[65])smem;
    for (int tid2 = bid; tid2 < 780; tid2 += NB) {
      int layer = tid2 / 156, r = tid2 % 156;
      int kt = r / 13, nt = r % 13;
      int k0 = kt * 64, n0 = nt * 64;
      __syncthreads();
#pragma unroll
      for (int i = 0; i < 16; ++i) {
        int e = t + 256 * i, rk = e >> 6, cn = e & 63;
        float v;
        if (nt < 12) {
          v = ldf(Wg, ((size_t)layer * 768 + k0 + rk) * 768 + n0 + cn, fF);
        } else {
          v = (cn < 8) ? F[(size_t)layer * 8 * 768 + (size_t)cn * 768 + k0 + rk] : 0.f;
        }
        tile[rk][cn] = v;
      }
      __syncthreads();
      size_t lbase = (size_t)layer * 832 * 768;
#pragma unroll
      for (int i = 0; i < 16; ++i) {
        int e = t + 256 * i, rn = e >> 6, ck = e & 63;
        float v = tile[ck][rn];
        unsigned short hi = f2b(v);
        float lo = v - b2f((unsigned int)hi);
        size_t o = lbase + (size_t)(n0 + rn) * 768 + k0 + ck;
        Bh[o] = hi;
        Bl[o] = f2b(lo);
      }
    }
  }

  gbar(bar);

  // ================= 5 GAT layers ========================================
  for (int l = 0; l < 5; ++l) {
    // ---- gemm: C = x @ B[l]^T (117 tiles; rest idle) ----
    if (bid < 117) {
      unsigned short(*Ah)[48] = (unsigned short(*)[48])smem;
      unsigned short(*Al)[48] = (unsigned short(*)[48])(smem + 6144);
      unsigned short(*Bhs)[48] = (unsigned short(*)[48])(smem + 12288);
      unsigned short(*Bls)[48] = (unsigned short(*)[48])(smem + 18432);
      int rt = bid % 9, ct = bid / 9;
      int quad = lane >> 4, lr = lane & 15;
      f32x4 acc[4];
#pragma unroll
      for (int c = 0; c < 4; ++c) acc[c] = (f32x4){0.f, 0.f, 0.f, 0.f};
      int sr = t >> 2, sc = t & 3;
      size_t lb = (size_t)l * 832 * 768;
      const uint4* Agh = (const uint4*)(xh + (size_t)(rt * 64 + sr) * 768);
      const uint4* Agl = (const uint4*)(xl + (size_t)(rt * 64 + sr) * 768);
      const uint4* Bgh = (const uint4*)(Bh + lb + (size_t)(ct * 64 + sr) * 768);
      const uint4* Bgl = (const uint4*)(Bl + lb + (size_t)(ct * 64 + sr) * 768);
      __syncthreads();
      for (int kk = 0; kk < 24; ++kk) {
        *(uint4*)&Ah[sr][sc * 8] = Agh[kk * 4 + sc];
        *(uint4*)&Al[sr][sc * 8] = Agl[kk * 4 + sc];
        *(uint4*)&Bhs[sr][sc * 8] = Bgh[kk * 4 + sc];
        *(uint4*)&Bls[sr][sc * 8] = Bgl[kk * 4 + sc];
        __syncthreads();
        s16x8 ah = *(const s16x8*)&Ah[wave * 16 + lr][quad * 8];
        s16x8 al = *(const s16x8*)&Al[wave * 16 + lr][quad * 8];
#pragma unroll
        for (int c = 0; c < 4; ++c) {
          s16x8 bh = *(const s16x8*)&Bhs[c * 16 + lr][quad * 8];
          s16x8 bl = *(const s16x8*)&Bls[c * 16 + lr][quad * 8];
          acc[c] = __builtin_amdgcn_mfma_f32_16x16x32_bf16(ah, bh, acc[c], 0, 0, 0);
          acc[c] = __builtin_amdgcn_mfma_f32_16x16x32_bf16(ah, bl, acc[c], 0, 0, 0);
          acc[c] = __builtin_amdgcn_mfma_f32_16x16x32_bf16(al, bh, acc[c], 0, 0, 0);
        }
        __syncthreads();
      }
      int row0 = rt * 64 + wave * 16 + quad * 4;
      int col0 = ct * 64 + lr;
#pragma unroll
      for (int c = 0; c < 4; ++c)
#pragma unroll
        for (int r = 0; r < 4; ++r)
          C[(size_t)(row0 + r) * 832 + col0 + c * 16] = acc[c][r];
    }

    gbar(bar);

    // ---- gat: per (node, feature) softmax-aggregate + GELU ----
    for (int c = bid; c < 1728; c += NB) {
      int idx = c * 256 + t;
      int n = idx / 768, d = idx - n * 768, h = d / 192;
      float aDv = C[(size_t)n * 832 + 772 + h];
      int e0 = csr_off[n], e1 = csr_off[n + 1];
      float num = 0.f, den = 0.f;
      for (int e = e0; e < e1; ++e) {
        int s = csr_src[e];
        float lg = C[(size_t)s * 832 + 768 + h] + aDv;
        float lrel = lg < 0.f ? 0.2f * lg : lg;
        lrel = fminf(fmaxf(lrel, -60.f), 40.f);
        float w = __expf(lrel);
        num += w * C[(size_t)s * 832 + d];
        den += w;
      }
      float g = gelu_exact(num / den + ldf(bG, (size_t)l * 768 + d, fF));
      xf[idx] = g;
      unsigned short hi = f2b(g);
      xh[idx] = hi;
      xl[idx] = f2b(g - b2f((unsigned int)hi));
    }

    gbar(bar);
  }

  // ================= P4: final layernorm ================================
  for (int r = bid * 4 + wave; r < 32768; r += NB * 4) {
    int b = r >> 9, s = r & 511;
    int sg = ldi(seg, (size_t)r, fI), tp = ldi(typ, (size_t)r, fI);
    int wrow = ldi(src, (size_t)r, fI);
    bool cls = (s == 0);
    float sum = 0.f, sq = 0.f;
    f32x4 vv[3];
    float vs[12];
    if (fF) {
      const f32x4* wr = (const f32x4*)((const float*)word + (size_t)wrow * 768);
      const f32x4* pr = (const f32x4*)((const float*)post + (size_t)s * 768);
      const f32x4* srp = (const f32x4*)((const float*)segt + (size_t)sg * 768);
      const f32x4* tr = (const f32x4*)((const float*)typt + (size_t)tp * 768);
      const f32x4* xr = (const f32x4*)(xf + (size_t)b * 9 * 768);
#pragma unroll
      for (int j = 0; j < 3; ++j) {
        int p = lane + 64 * j;
        f32x4 a = cls ? xr[p] : wr[p];
        a += pr[p]; a += srp[p]; a += tr[p];
        vv[j] = a;
#pragma unroll
        for (int c = 0; c < 4; ++c) { sum += a[c]; sq += a[c] * a[c]; }
      }
    } else {
#pragma unroll
      for (int j = 0; j < 12; ++j) {
        int d = lane + 64 * j;
        float xv = cls ? xf[(size_t)b * 9 * 768 + d] : ldf(word, (size_t)wrow * 768 + d, fF);
        xv += ldf(post, (size_t)s * 768 + d, fF);
        xv += ldf(segt, (size_t)sg * 768 + d, fF);
        xv += ldf(typt, (size_t)tp * 768 + d, fF);
        vs[j] = xv;
        sum += xv; sq += xv * xv;
      }
    }
#pragma unroll
    for (int o = 32; o > 0; o >>= 1) { sum += __shfl_down(sum, o); sq += __shfl_down(sq, o); }
    sum = __shfl(sum, 0); sq = __shfl(sq, 0);
    float mu = sum * (1.f / 768.f);
    float var = fmaxf(sq * (1.f / 768.f) - mu * mu, 0.f);
    float rstd = rsqrtf(var + 1e-6f);
    if (fF) {
      const f32x4* gm = (const f32x4*)gamma;
      const f32x4* bt = (const f32x4*)beta;
      f32x4* orow = (f32x4*)((float*)out + (size_t)r * 768);
#pragma unroll
      for (int j = 0; j < 3; ++j) {
        int p = lane + 64 * j;
        f32x4 g4 = gm[p], b4 = bt[p], y;
#pragma unroll
        for (int c = 0; c < 4; ++c) y[c] = g4[c] * (vv[j][c] - mu) * rstd + b4[c];
        __builtin_nontemporal_store(y, &orow[p]);
      }
    } else {
#pragma unroll
      for (int j = 0; j < 12; ++j) {
        int d = lane + 64 * j;
        float y = ldf(gamma, (size_t)d, fF) * (vs[j] - mu) * rstd + ldf(beta, (size_t)d, fF);
        ((unsigned short*)out)[(size_t)r * 768 + d] = f2b(y);
      }
    }
  }
}

extern "C" void kernel_launch(void* const* d_in, const int* in_sizes, int n_in,
                              void* d_out, int out_size, void* d_ws, size_t ws_size,
                              hipStream_t stream) {
  const void* src  = d_in[0];
  const void* seg  = d_in[1];
  const void* typ  = d_in[2];
  const void* pos  = d_in[3];
  const void* sst  = d_in[4];
  const void* sen  = d_in[5];
  const void* edge = d_in[6];
  const void* word = d_in[7];
  const void* post = d_in[8];
  const void* segt = d_in[9];
  const void* typt = d_in[10];
  const void* gamma = d_in[11];
  const void* beta  = d_in[12];
  const void* Wg    = d_in[13];
  const void* aS    = d_in[14];
  const void* aD    = d_in[15];
  const void* bG    = d_in[16];

  char* ws = (char*)d_ws;
  float* xf = (float*)(ws);                               //  1,769,472
  float* C  = (float*)(ws + 1769472);                     //  1,916,928
  unsigned short* xh = (unsigned short*)(ws + 3686400);   //    884,736
  unsigned short* xl = (unsigned short*)(ws + 4571136);   //    884,736
  unsigned short* Bh = (unsigned short*)(ws + 5455872);   //  6,389,760
  unsigned short* Bl = (unsigned short*)(ws + 11845632);  //  6,389,760
  float* F = (float*)(ws + 18235392);                     //    122,880
  int* csr_off = (int*)(ws + 18358272);                   //      2,320 (pad)
  int* csr_src = (int*)(ws + 18360592);                   //     35,072
  int* bar     = (int*)(ws + 18395664);                   //         16

  hipMemsetAsync(bar, 0, 16, stream);
  k_all<<<dim3(NB), dim3(256), 0, stream>>>(src, seg, typ, pos, sst, sen, edge, word,
                                            post, segt, typt, gamma, beta, Wg, aS, aD, bG,
                                            F, xh, xl, Bh, Bl, C, xf, csr_off, csr_src,
                                            bar, d_out);
}